// Round 3
// baseline (961.363 us; speedup 1.0000x reference)
//
#include <hip/hip_runtime.h>
#include <hip/hip_fp8.h>
#include <stdint.h>

#define DEVI __device__ __forceinline__

typedef unsigned short u16;
typedef uint8_t u8;
typedef __attribute__((ext_vector_type(8))) __bf16 bf16x8;   // MFMA bf16 A/B frag
typedef __attribute__((ext_vector_type(4))) float f32x4;     // MFMA C/D frag

DEVI float b2f(u16 u) { union { unsigned int i; float f; } v; v.i = ((unsigned int)u) << 16; return v.f; }
DEVI u16 f2b(float f) {
  union { float f; unsigned int i; } v; v.f = f;
  unsigned int r = v.i + 0x7fffu + ((v.i >> 16) & 1u);
  return (u16)(r >> 16);
}
DEVI u8 f2f8(float f) { __hip_fp8_e4m3 t(f); return t.__x; }
DEVI float f82f(u8 u) { __hip_fp8_e4m3 t; t.__x = u; return (float)t; }

DEVI void gld_lds16(const void* g, void* l) {
  __builtin_amdgcn_global_load_lds((const __attribute__((address_space(1))) unsigned int*)g,
                                   (__attribute__((address_space(3))) unsigned int*)l, 16, 0, 0);
}

// qkv staging-row permutation: within q/k sections, permuted row 2p -> p, 2p+1 -> p+512
DEVI int qkv_permrow(int r) {
  const int sec = r >> 10, w = r & 1023;
  const int pw = (sec < 2) ? (((w & 1) ? 512 : 0) + (w >> 1)) : w;
  return (sec << 10) | pw;
}

// =======================================================================
// Prep kernels
// =======================================================================

// transposed ternary cos/sin table: cs[p*4096 + pos] = packed(int8 c, int8 s)
__global__ __launch_bounds__(256) void k_cs_table(short* __restrict__ cs) {
  const int idx = blockIdx.x * 256 + threadIdx.x;   // 512*4096 entries
  const int p = idx >> 12, pos = idx & 4095;
  const float e = (float)p * (1.0f / 512.0f);
  const float invf = 1.0f / powf(10000.0f, e);
  const float ang = (float)pos * invf;
  const signed char c8 = (signed char)rintf(cosf(ang));
  const signed char s8 = (signed char)rintf(sinf(ang));
  cs[idx] = (short)((unsigned char)c8 | ((unsigned short)(unsigned char)s8 << 8));
}

__global__ __launch_bounds__(256) void k_rmsnorm(const float* __restrict__ x,
                                                 const float* __restrict__ g,
                                                 u16* __restrict__ h) {
  const int row = blockIdx.x;
  const int t = threadIdx.x;
  const float4 v = ((const float4*)(x + (size_t)row * 1024))[t];
  float ss = v.x * v.x + v.y * v.y + v.z * v.z + v.w * v.w;
  for (int off = 32; off > 0; off >>= 1) ss += __shfl_down(ss, off);
  __shared__ float red[4];
  if ((t & 63) == 0) red[t >> 6] = ss;
  __syncthreads();
  const float tot = red[0] + red[1] + red[2] + red[3];
  const float sc = rsqrtf(tot * (1.0f / 1024.0f) + 1e-6f);
  const float4 gv = ((const float4*)g)[t];
  ushort4 o;
  o.x = f2b(v.x * sc * gv.x); o.y = f2b(v.y * sc * gv.y);
  o.z = f2b(v.z * sc * gv.z); o.w = f2b(v.w * sc * gv.w);
  *(ushort4*)(h + (size_t)row * 1024 + t * 4) = o;
}

// dst[c][r] = (bf16) src[r][c]
__global__ __launch_bounds__(256) void k_transpose_cast(const float* __restrict__ src,
                                                        int rows, int cols,
                                                        u16* __restrict__ dst) {
  __shared__ float tile[32][33];
  const int c0 = blockIdx.x * 32, r0 = blockIdx.y * 32;
  const int tx = threadIdx.x, ty = threadIdx.y;
  for (int i = 0; i < 32; i += 8)
    tile[ty + i][tx] = src[(size_t)(r0 + ty + i) * cols + c0 + tx];
  __syncthreads();
  for (int i = 0; i < 32; i += 8)
    dst[(size_t)(c0 + ty + i) * rows + r0 + tx] = f2b(tile[tx][ty + i]);
}

// vt[b][d][s] = fp8( v[(b*4096+s)*1024 + d] )
__global__ __launch_bounds__(256) void k_vt(const u16* __restrict__ v, u8* __restrict__ vt) {
  __shared__ u16 tile[32][33];
  const int b = blockIdx.z;
  const int s0 = blockIdx.x * 32, d0 = blockIdx.y * 32;
  const int tx = threadIdx.x, ty = threadIdx.y;
  for (int i = 0; i < 32; i += 8)
    tile[ty + i][tx] = v[(size_t)(b * 4096 + s0 + ty + i) * 1024 + d0 + tx];
  __syncthreads();
  for (int i = 0; i < 32; i += 8)
    vt[(size_t)(b * 1024 + d0 + ty + i) * 4096 + s0 + tx] = f2f8(b2f(tile[tx][ty + i]));
}

// =======================================================================
// bf16 MFMA GEMM core (m97 structure, BK=32). PERM=1: qkv_permrow on B rows.
// =======================================================================
template <int PERM>
DEVI void gemm_tile(const u16* __restrict__ A, int lda,
                    const u16* __restrict__ B, int ldb,
                    int K, int m0, int n0,
                    u16* As, u16* Bs, f32x4 acc[4][4]) {
  const int t = threadIdx.x;
  const int sr = t >> 2;
  const int sc = (t & 3) * 8;
  int br0 = n0 + sr, br1 = n0 + 64 + sr;
  if (PERM) { br0 = qkv_permrow(br0); br1 = qkv_permrow(br1); }
  const u16* Ag0 = A + (size_t)(m0 + sr) * lda + sc;
  const u16* Ag1 = A + (size_t)(m0 + 64 + sr) * lda + sc;
  const u16* Bg0 = B + (size_t)br0 * ldb + sc;
  const u16* Bg1 = B + (size_t)br1 * ldb + sc;
  u16* Asw0 = As + t * 8;
  u16* Asw1 = As + 2048 + t * 8;
  u16* Bsw0 = Bs + t * 8;
  u16* Bsw1 = Bs + 2048 + t * 8;

  const int lane = t & 63, qd = lane >> 4, l16 = lane & 15;
  const int wave = t >> 6;
  const int wm = (wave >> 1) * 64, wn = (wave & 1) * 64;
  const u16* Ard = As + (size_t)(wm + l16) * 32 + qd * 8;
  const u16* Brd = Bs + (size_t)(wn + l16) * 32 + qd * 8;

  for (int k0 = 0; k0 < K; k0 += 32) {
    gld_lds16(Ag0 + k0, Asw0);
    gld_lds16(Ag1 + k0, Asw1);
    gld_lds16(Bg0 + k0, Bsw0);
    gld_lds16(Bg1 + k0, Bsw1);
    __builtin_amdgcn_s_waitcnt(0);
    __syncthreads();
    bf16x8 af[4], bfv[4];
#pragma unroll
    for (int i = 0; i < 4; i++) af[i] = *(const bf16x8*)(Ard + i * 16 * 32);
#pragma unroll
    for (int j = 0; j < 4; j++) bfv[j] = *(const bf16x8*)(Brd + j * 16 * 32);
#pragma unroll
    for (int i = 0; i < 4; i++)
#pragma unroll
      for (int j = 0; j < 4; j++)
        acc[i][j] = __builtin_amdgcn_mfma_f32_16x16x32_bf16(af[i], bfv[j], acc[i][j], 0, 0, 0);
    __syncthreads();
  }
}

// =======================================================================
// fp8 MFMA GEMM core (BK=64): half the staged bytes per K-element, half the
// barrier count. A,B both e4m3; same-rate MFMA as bf16 (m145 structure).
// Both operands staged with identical k-layout -> dot pairing is consistent.
// =======================================================================
DEVI void gemm_tile_f8(const u8* __restrict__ A, int lda,
                       const u8* __restrict__ B, int ldb,
                       int K, int m0, int n0,
                       u8* As, u8* Bs, f32x4 acc[4][4]) {
  const int t = threadIdx.x;
  const int sr = t >> 2;              // row 0..63 within half-tile
  const int sc = (t & 3) * 16;        // byte col 0..48
  const u8* Ag0 = A + (size_t)(m0 + sr) * lda + sc;
  const u8* Ag1 = A + (size_t)(m0 + 64 + sr) * lda + sc;
  const u8* Bg0 = B + (size_t)(n0 + sr) * ldb + sc;
  const u8* Bg1 = B + (size_t)(n0 + 64 + sr) * ldb + sc;
  u8* Asw0 = As + t * 16;
  u8* Asw1 = As + 4096 + t * 16;
  u8* Bsw0 = Bs + t * 16;
  u8* Bsw1 = Bs + 4096 + t * 16;

  const int lane = t & 63, qd = lane >> 4, l16 = lane & 15;
  const int wave = t >> 6;
  const int wm = (wave >> 1) * 64, wn = (wave & 1) * 64;
  const u8* Ard = As + (size_t)(wm + l16) * 64 + qd * 8;
  const u8* Brd = Bs + (size_t)(wn + l16) * 64 + qd * 8;

  for (int k0 = 0; k0 < K; k0 += 64) {
    gld_lds16(Ag0 + k0, Asw0);
    gld_lds16(Ag1 + k0, Asw1);
    gld_lds16(Bg0 + k0, Bsw0);
    gld_lds16(Bg1 + k0, Bsw1);
    __builtin_amdgcn_s_waitcnt(0);
    __syncthreads();
    long a0[4], a1[4], b0[4], b1[4];
#pragma unroll
    for (int i = 0; i < 4; i++) {
      a0[i] = *(const long*)(Ard + i * 16 * 64);
      a1[i] = *(const long*)(Ard + i * 16 * 64 + 32);
    }
#pragma unroll
    for (int j = 0; j < 4; j++) {
      b0[j] = *(const long*)(Brd + j * 16 * 64);
      b1[j] = *(const long*)(Brd + j * 16 * 64 + 32);
    }
#pragma unroll
    for (int i = 0; i < 4; i++)
#pragma unroll
      for (int j = 0; j < 4; j++) {
        acc[i][j] = __builtin_amdgcn_mfma_f32_16x16x32_fp8_fp8(a0[i], b0[j], acc[i][j], 0, 0, 0);
        acc[i][j] = __builtin_amdgcn_mfma_f32_16x16x32_fp8_fp8(a1[i], b1[j], acc[i][j], 0, 0, 0);
      }
    __syncthreads();
  }
}

#define ACC_INIT()                                               \
  f32x4 acc[4][4];                                               \
  _Pragma("unroll") for (int i = 0; i < 4; i++)                  \
      _Pragma("unroll") for (int j = 0; j < 4; j++)              \
          acc[i][j] = f32x4{0.f, 0.f, 0.f, 0.f};

#define GEMM_EPI_IDX()                                           \
  const int t = threadIdx.x, lane = t & 63, qd = lane >> 4,      \
            l16 = lane & 15, wave = t >> 6;                      \
  const int wm = (wave >> 1) * 64, wn = (wave & 1) * 64;         \
  (void)t;

// C/D layout (verified m89/m91, dtype-independent): col = lane&15, row = quad*4 + reg

// qkv GEMM (bf16, natural block mapping): permuted-B staging; epilogue applies
// ternary rope via shfl_xor(1), writes q,k as fp8 and v as bf16.
__global__ __launch_bounds__(256) void k_gemm_qkv(const u16* __restrict__ A, const u16* __restrict__ Bt,
                                                  const float* __restrict__ bias,
                                                  const short* __restrict__ cst,
                                                  u8* __restrict__ q, u8* __restrict__ k,
                                                  u16* __restrict__ v) {
  __shared__ alignas(16) u16 As[4096], Bs[4096];
  ACC_INIT();
  const int m0 = blockIdx.y * 128, n0 = blockIdx.x * 128;
  gemm_tile<1>(A, 1024, Bt, 1024, 1024, m0, n0, As, Bs, acc);
  GEMM_EPI_IDX();
  const int sec = n0 >> 10;          // 0=q 1=k 2=v (uniform per block)
  if (sec == 2) {
#pragma unroll
    for (int i = 0; i < 4; i++) {
      const int mb = m0 + wm + i * 16 + qd * 4;
#pragma unroll
      for (int j = 0; j < 4; j++) {
        const int col = n0 + wn + j * 16 + l16;
        const float bv = bias[col];
#pragma unroll
        for (int r = 0; r < 4; r++)
          v[(size_t)(mb + r) * 1024 + (col - 2048)] = f2b(acc[i][j][r] + bv);
      }
    }
  } else {
    u8* dst = (sec == 0) ? q : k;
#pragma unroll
    for (int i = 0; i < 4; i++) {
      const int mb = m0 + wm + i * 16 + qd * 4;
#pragma unroll
      for (int j = 0; j < 4; j++) {
        const int n = n0 + wn + j * 16 + l16;           // permuted col
        const int w = n & 1023;
        const int odd = w & 1;
        const int p = w >> 1;                           // rope pair index 0..511
        const int physw = odd ? p + 512 : p;
        const float bv = bias[(n & ~1023) | physw];
        // one vector load covers cos/sin for all 4 rows of this quad
        const ushort4 cs4 = *(const ushort4*)(cst + (p << 12) + (mb & 4095));
#pragma unroll
        for (int r = 0; r < 4; r++) {
          const unsigned short cspack = (r == 0) ? cs4.x : (r == 1) ? cs4.y : (r == 2) ? cs4.z : cs4.w;
          const float c = (float)(signed char)(cspack & 0xff);
          const float s = (float)(signed char)(cspack >> 8);
          const float val = acc[i][j][r] + bv;
          const float partner = __shfl_xor(val, 1);
          const float outv = odd ? (val * c + partner * s) : (val * c - partner * s);
          dst[(size_t)(mb + r) * 1024 + physw] = f2f8(outv);
        }
      }
    }
  }
}

// P = 3^(q k^T / 32) fp8, row sums ls (of the quantized values). XCD 16m x 8n.
__global__ __launch_bounds__(256) void k_gemm_scores(const u8* __restrict__ q, const u8* __restrict__ kk,
                                                     u8* __restrict__ P, float* __restrict__ ls, int b0) {
  __shared__ alignas(16) u8 As[8192], Bs[8192];
  ACC_INIT();
  const int zz = blockIdx.z, b = b0 + zz;
  const u8* A = q + (size_t)b * 4096 * 1024;
  const u8* Bt = kk + (size_t)b * 4096 * 1024;
  const int bid = blockIdx.y * 32 + blockIdx.x;
  const int xcd = bid & 7, idx = bid >> 3;
  const int m0 = ((xcd >> 2) * 16 + (idx & 15)) * 128;
  const int n0 = ((xcd & 3) * 8 + (idx >> 4)) * 128;
  gemm_tile_f8(A, 1024, Bt, 1024, 1024, m0, n0, As, Bs, acc);
  GEMM_EPI_IDX();
  const float C3 = 0.04953007814753613f;  // log2(3) / 32
  const size_t Pb = (size_t)zz * 4096 * 4096;
  f32x4 rowp[4];
#pragma unroll
  for (int i = 0; i < 4; i++) rowp[i] = f32x4{0.f, 0.f, 0.f, 0.f};
#pragma unroll
  for (int i = 0; i < 4; i++) {
    const int mb = m0 + wm + i * 16 + qd * 4;
#pragma unroll
    for (int j = 0; j < 4; j++) {
      const int col = n0 + wn + j * 16 + l16;
#pragma unroll
      for (int r = 0; r < 4; r++) {
        const float pv = exp2f(acc[i][j][r] * C3);
        const u8 pq = f2f8(pv);
        P[Pb + (size_t)(mb + r) * 4096 + col] = pq;
        rowp[i][r] += f82f(pq);   // numerator/denominator consistent
      }
    }
  }
#pragma unroll
  for (int m = 1; m < 16; m <<= 1)
#pragma unroll
    for (int i = 0; i < 4; i++) {
      rowp[i].x += __shfl_xor(rowp[i].x, m);
      rowp[i].y += __shfl_xor(rowp[i].y, m);
      rowp[i].z += __shfl_xor(rowp[i].z, m);
      rowp[i].w += __shfl_xor(rowp[i].w, m);
    }
  if (l16 == 0) {
#pragma unroll
    for (int i = 0; i < 4; i++) {
      const int mb = m0 + wm + i * 16 + qd * 4;
#pragma unroll
      for (int r = 0; r < 4; r++)
        atomicAdd(ls + (size_t)b * 4096 + mb + r, rowp[i][r]);
    }
  }
}

// o = (P @ V) / ls  (fp8 x fp8 -> bf16). XCD 8m x 4n.
__global__ __launch_bounds__(256) void k_gemm_pv(const u8* __restrict__ P, const u8* __restrict__ vt,
                                                 const float* __restrict__ ls, u16* __restrict__ o, int b0) {
  __shared__ alignas(16) u8 As[8192], Bs[8192];
  ACC_INIT();
  const int zz = blockIdx.z, b = b0 + zz;
  const u8* A = P + (size_t)zz * 4096 * 4096;
  const u8* Bt = vt + (size_t)b * 1024 * 4096;
  const int bid = blockIdx.y * 8 + blockIdx.x;
  const int xcd = bid & 7, idx = bid >> 3;
  const int m0 = ((xcd >> 1) * 8 + (idx & 7)) * 128;
  const int n0 = ((xcd & 1) * 4 + (idx >> 3)) * 128;
  gemm_tile_f8(A, 4096, Bt, 4096, 4096, m0, n0, As, Bs, acc);
  GEMM_EPI_IDX();
#pragma unroll
  for (int i = 0; i < 4; i++) {
    const int mb = m0 + wm + i * 16 + qd * 4;
    f32x4 inv;
#pragma unroll
    for (int r = 0; r < 4; r++) inv[r] = 1.0f / ls[(size_t)b * 4096 + mb + r];
#pragma unroll
    for (int j = 0; j < 4; j++) {
      const int col = n0 + wn + j * 16 + l16;
#pragma unroll
      for (int r = 0; r < 4; r++)
        o[(size_t)(b * 4096 + mb + r) * 1024 + col] = f2b(acc[i][j][r] * inv[r]);
    }
  }
}

// out = o @ WprojT^T + bias + x  (bf16 GEMM, natural mapping, fp32 out)
__global__ __launch_bounds__(256) void k_gemm_proj(const u16* __restrict__ A, const u16* __restrict__ Bt,
                                                   const float* __restrict__ bias, const float* __restrict__ x,
                                                   float* __restrict__ out) {
  __shared__ alignas(16) u16 As[4096], Bs[4096];
  ACC_INIT();
  const int m0 = blockIdx.y * 128, n0 = blockIdx.x * 128;
  gemm_tile<0>(A, 1024, Bt, 1024, 1024, m0, n0, As, Bs, acc);
  GEMM_EPI_IDX();
#pragma unroll
  for (int i = 0; i < 4; i++) {
    const int mb = m0 + wm + i * 16 + qd * 4;
#pragma unroll
    for (int j = 0; j < 4; j++) {
      const int col = n0 + wn + j * 16 + l16;
      const float bv = bias[col];
#pragma unroll
      for (int r = 0; r < 4; r++) {
        const size_t idxo = (size_t)(mb + r) * 1024 + col;
        out[idxo] = acc[i][j][r] + bv + x[idxo];
      }
    }
  }
}

// =======================================================================
extern "C" void kernel_launch(void* const* d_in, const int* in_sizes, int n_in,
                              void* d_out, int out_size, void* d_ws, size_t ws_size,
                              hipStream_t stream) {
  const float* x     = (const float*)d_in[0];
  const float* g     = (const float*)d_in[1];
  const float* wqkv  = (const float*)d_in[2];
  const float* bqkv  = (const float*)d_in[3];
  const float* wproj = (const float*)d_in[4];
  const float* bproj = (const float*)d_in[5];
  float* out = (float*)d_out;

  char* wsp = (char*)d_ws;
  size_t off = 0;
  auto take = [&](size_t bytes) -> void* {
    off = (off + 255) & ~(size_t)255;
    void* r = wsp + off;
    off += bytes;
    return r;
  };
  u16* h    = (u16*)take(16384ull * 1024 * 2);   // rmsnorm out; reused as o (PV out)
  u16* wqT  = (u16*)take(3072ull * 1024 * 2);
  u16* wpT  = (u16*)take(1024ull * 1024 * 2);
  u8*  q    = (u8*)take(16384ull * 1024);
  u8*  k    = (u8*)take(16384ull * 1024);
  u16* v    = (u16*)take(16384ull * 1024 * 2);
  u8*  vt   = (u8*)take(4ull * 1024 * 4096);
  short* cst = (short*)take(512ull * 4096 * 2);
  float* ls = (float*)take(16384ull * 4);
  off = (off + 255) & ~(size_t)255;
  int nb = 4;
  while (nb > 1 && off + (size_t)nb * 4096 * 4096 > ws_size) nb >>= 1;
  u8* P = (u8*)(wsp + off);

  k_cs_table<<<8192, 256, 0, stream>>>(cst);
  k_transpose_cast<<<dim3(3072 / 32, 1024 / 32), dim3(32, 8), 0, stream>>>(wqkv, 1024, 3072, wqT);
  k_transpose_cast<<<dim3(1024 / 32, 1024 / 32), dim3(32, 8), 0, stream>>>(wproj, 1024, 1024, wpT);
  k_rmsnorm<<<16384, 256, 0, stream>>>(x, g, h);
  k_gemm_qkv<<<dim3(24, 128), 256, 0, stream>>>(h, wqT, bqkv, cst, q, k, v);
  k_vt<<<dim3(128, 32, 4), dim3(32, 8), 0, stream>>>(v, vt);
  hipMemsetAsync(ls, 0, 16384 * 4, stream);
  for (int b0 = 0; b0 < 4; b0 += nb) {
    k_gemm_scores<<<dim3(32, 32, nb), 256, 0, stream>>>(q, k, P, ls, b0);
    k_gemm_pv<<<dim3(8, 32, nb), 256, 0, stream>>>(P, vt, ls, h /*=o*/, b0);
  }
  k_gemm_proj<<<dim3(8, 128), 256, 0, stream>>>(h /*=o*/, wpT, bproj, x, out);
}

// Round 4
// 658.232 us; speedup vs baseline: 1.4605x; 1.4605x over previous
//
#include <hip/hip_runtime.h>
#include <hip/hip_fp8.h>
#include <stdint.h>

#define DEVI __device__ __forceinline__

typedef unsigned short u16;
typedef uint8_t u8;
typedef __attribute__((ext_vector_type(8))) __bf16 bf16x8;   // MFMA bf16 A/B frag
typedef __attribute__((ext_vector_type(4))) float f32x4;     // MFMA C/D frag

DEVI float b2f(u16 u) { union { unsigned int i; float f; } v; v.i = ((unsigned int)u) << 16; return v.f; }
DEVI u16 f2b(float f) {
  union { float f; unsigned int i; } v; v.f = f;
  unsigned int r = v.i + 0x7fffu + ((v.i >> 16) & 1u);
  return (u16)(r >> 16);
}
DEVI u8 f2f8(float f) { __hip_fp8_e4m3 t(f); return t.__x; }
DEVI float f82f(u8 u) { __hip_fp8_e4m3 t; t.__x = u; return (float)t; }

DEVI void gld_lds16(const void* g, void* l) {
  __builtin_amdgcn_global_load_lds((const __attribute__((address_space(1))) unsigned int*)g,
                                   (__attribute__((address_space(3))) unsigned int*)l, 16, 0, 0);
}

// qkv staging-row permutation: within q/k sections, permuted row 2p -> p, 2p+1 -> p+512
DEVI int qkv_permrow(int r) {
  const int sec = r >> 10, w = r & 1023;
  const int pw = (sec < 2) ? (((w & 1) ? 512 : 0) + (w >> 1)) : w;
  return (sec << 10) | pw;
}

// =======================================================================
// Prep kernels
// =======================================================================

// transposed ternary cos/sin table: cs[p*4096 + pos] = packed(int8 c, int8 s)
__global__ __launch_bounds__(256) void k_cs_table(short* __restrict__ cs) {
  const int idx = blockIdx.x * 256 + threadIdx.x;   // 512*4096 entries
  const int p = idx >> 12, pos = idx & 4095;
  const float e = (float)p * (1.0f / 512.0f);
  const float invf = 1.0f / powf(10000.0f, e);
  const float ang = (float)pos * invf;
  const signed char c8 = (signed char)rintf(cosf(ang));
  const signed char s8 = (signed char)rintf(sinf(ang));
  cs[idx] = (short)((unsigned char)c8 | ((unsigned short)(unsigned char)s8 << 8));
}

__global__ __launch_bounds__(256) void k_rmsnorm(const float* __restrict__ x,
                                                 const float* __restrict__ g,
                                                 u16* __restrict__ h) {
  const int row = blockIdx.x;
  const int t = threadIdx.x;
  const float4 v = ((const float4*)(x + (size_t)row * 1024))[t];
  float ss = v.x * v.x + v.y * v.y + v.z * v.z + v.w * v.w;
  for (int off = 32; off > 0; off >>= 1) ss += __shfl_down(ss, off);
  __shared__ float red[4];
  if ((t & 63) == 0) red[t >> 6] = ss;
  __syncthreads();
  const float tot = red[0] + red[1] + red[2] + red[3];
  const float sc = rsqrtf(tot * (1.0f / 1024.0f) + 1e-6f);
  const float4 gv = ((const float4*)g)[t];
  ushort4 o;
  o.x = f2b(v.x * sc * gv.x); o.y = f2b(v.y * sc * gv.y);
  o.z = f2b(v.z * sc * gv.z); o.w = f2b(v.w * sc * gv.w);
  *(ushort4*)(h + (size_t)row * 1024 + t * 4) = o;
}

// dst[c][r] = (bf16) src[r][c]
__global__ __launch_bounds__(256) void k_transpose_cast(const float* __restrict__ src,
                                                        int rows, int cols,
                                                        u16* __restrict__ dst) {
  __shared__ float tile[32][33];
  const int c0 = blockIdx.x * 32, r0 = blockIdx.y * 32;
  const int tx = threadIdx.x, ty = threadIdx.y;
  for (int i = 0; i < 32; i += 8)
    tile[ty + i][tx] = src[(size_t)(r0 + ty + i) * cols + c0 + tx];
  __syncthreads();
  for (int i = 0; i < 32; i += 8)
    dst[(size_t)(c0 + ty + i) * rows + r0 + tx] = f2b(tile[tx][ty + i]);
}

// vt[b][d][s] = fp8( v[(b*4096+s)*1024 + d] )
__global__ __launch_bounds__(256) void k_vt(const u16* __restrict__ v, u8* __restrict__ vt) {
  __shared__ u16 tile[32][33];
  const int b = blockIdx.z;
  const int s0 = blockIdx.x * 32, d0 = blockIdx.y * 32;
  const int tx = threadIdx.x, ty = threadIdx.y;
  for (int i = 0; i < 32; i += 8)
    tile[ty + i][tx] = v[(size_t)(b * 4096 + s0 + ty + i) * 1024 + d0 + tx];
  __syncthreads();
  for (int i = 0; i < 32; i += 8)
    vt[(size_t)(b * 1024 + d0 + ty + i) * 4096 + s0 + tx] = f2f8(b2f(tile[tx][ty + i]));
}

// =======================================================================
// bf16 MFMA GEMM core (m97 structure, BK=32). PERM=1: qkv_permrow on B rows.
// =======================================================================
template <int PERM>
DEVI void gemm_tile(const u16* __restrict__ A, int lda,
                    const u16* __restrict__ B, int ldb,
                    int K, int m0, int n0,
                    u16* As, u16* Bs, f32x4 acc[4][4]) {
  const int t = threadIdx.x;
  const int sr = t >> 2;
  const int sc = (t & 3) * 8;
  int br0 = n0 + sr, br1 = n0 + 64 + sr;
  if (PERM) { br0 = qkv_permrow(br0); br1 = qkv_permrow(br1); }
  const u16* Ag0 = A + (size_t)(m0 + sr) * lda + sc;
  const u16* Ag1 = A + (size_t)(m0 + 64 + sr) * lda + sc;
  const u16* Bg0 = B + (size_t)br0 * ldb + sc;
  const u16* Bg1 = B + (size_t)br1 * ldb + sc;
  u16* Asw0 = As + t * 8;
  u16* Asw1 = As + 2048 + t * 8;
  u16* Bsw0 = Bs + t * 8;
  u16* Bsw1 = Bs + 2048 + t * 8;

  const int lane = t & 63, qd = lane >> 4, l16 = lane & 15;
  const int wave = t >> 6;
  const int wm = (wave >> 1) * 64, wn = (wave & 1) * 64;
  const u16* Ard = As + (size_t)(wm + l16) * 32 + qd * 8;
  const u16* Brd = Bs + (size_t)(wn + l16) * 32 + qd * 8;

  for (int k0 = 0; k0 < K; k0 += 32) {
    gld_lds16(Ag0 + k0, Asw0);
    gld_lds16(Ag1 + k0, Asw1);
    gld_lds16(Bg0 + k0, Bsw0);
    gld_lds16(Bg1 + k0, Bsw1);
    __builtin_amdgcn_s_waitcnt(0);
    __syncthreads();
    bf16x8 af[4], bfv[4];
#pragma unroll
    for (int i = 0; i < 4; i++) af[i] = *(const bf16x8*)(Ard + i * 16 * 32);
#pragma unroll
    for (int j = 0; j < 4; j++) bfv[j] = *(const bf16x8*)(Brd + j * 16 * 32);
#pragma unroll
    for (int i = 0; i < 4; i++)
#pragma unroll
      for (int j = 0; j < 4; j++)
        acc[i][j] = __builtin_amdgcn_mfma_f32_16x16x32_bf16(af[i], bfv[j], acc[i][j], 0, 0, 0);
    __syncthreads();
  }
}

// =======================================================================
// fp8 MFMA GEMM core (BK=64), XOR-swizzled LDS chunks.
// Staging: lane t loads GLOBAL chunk (t&3)^((t>>3)&3) of row t>>2 into fixed
// LDS slot t*16  =>  LDS row r physical chunk p holds global chunk p^((r>>1)&3).
// Reads then hit all 32 banks exactly 4-deep (wave64 b64 minimum).
// =======================================================================
DEVI void gemm_tile_f8(const u8* __restrict__ A, int lda,
                       const u8* __restrict__ B, int ldb,
                       int K, int m0, int n0,
                       u8* As, u8* Bs, f32x4 acc[4][4]) {
  const int t = threadIdx.x;
  const int sr = t >> 2;                              // row 0..63 within half-tile
  const int sc = ((t & 3) ^ ((t >> 3) & 3)) << 4;     // swizzled global 16B chunk
  const u8* Ag0 = A + (size_t)(m0 + sr) * lda + sc;
  const u8* Ag1 = A + (size_t)(m0 + 64 + sr) * lda + sc;
  const u8* Bg0 = B + (size_t)(n0 + sr) * ldb + sc;
  const u8* Bg1 = B + (size_t)(n0 + 64 + sr) * ldb + sc;
  u8* Asw0 = As + t * 16;
  u8* Asw1 = As + 4096 + t * 16;
  u8* Bsw0 = Bs + t * 16;
  u8* Bsw1 = Bs + 4096 + t * 16;

  const int lane = t & 63, qd = lane >> 4, l16 = lane & 15;
  const int wave = t >> 6;
  const int wm = (wave >> 1) * 64, wn = (wave & 1) * 64;
  const int f = (l16 >> 1) & 3;                       // row swizzle key
  const int c0 = (((qd >> 1) ^ f) << 4) + ((qd & 1) << 3);  // k 0..31 chunk
  const u8* Ard0 = As + (size_t)(wm + l16) * 64 + c0;
  const u8* Ard1 = As + (size_t)(wm + l16) * 64 + (c0 ^ 32); // k 32..63 chunk
  const u8* Brd0 = Bs + (size_t)(wn + l16) * 64 + c0;
  const u8* Brd1 = Bs + (size_t)(wn + l16) * 64 + (c0 ^ 32);

  for (int k0 = 0; k0 < K; k0 += 64) {
    gld_lds16(Ag0 + k0, Asw0);
    gld_lds16(Ag1 + k0, Asw1);
    gld_lds16(Bg0 + k0, Bsw0);
    gld_lds16(Bg1 + k0, Bsw1);
    __builtin_amdgcn_s_waitcnt(0);
    __syncthreads();
    long a0[4], a1[4], b0[4], b1[4];
#pragma unroll
    for (int i = 0; i < 4; i++) {
      a0[i] = *(const long*)(Ard0 + i * 1024);
      a1[i] = *(const long*)(Ard1 + i * 1024);
    }
#pragma unroll
    for (int j = 0; j < 4; j++) {
      b0[j] = *(const long*)(Brd0 + j * 1024);
      b1[j] = *(const long*)(Brd1 + j * 1024);
    }
#pragma unroll
    for (int i = 0; i < 4; i++)
#pragma unroll
      for (int j = 0; j < 4; j++) {
        acc[i][j] = __builtin_amdgcn_mfma_f32_16x16x32_fp8_fp8(a0[i], b0[j], acc[i][j], 0, 0, 0);
        acc[i][j] = __builtin_amdgcn_mfma_f32_16x16x32_fp8_fp8(a1[i], b1[j], acc[i][j], 0, 0, 0);
      }
    __syncthreads();
  }
}

#define ACC_INIT()                                               \
  f32x4 acc[4][4];                                               \
  _Pragma("unroll") for (int i = 0; i < 4; i++)                  \
      _Pragma("unroll") for (int j = 0; j < 4; j++)              \
          acc[i][j] = f32x4{0.f, 0.f, 0.f, 0.f};

#define GEMM_EPI_IDX()                                           \
  const int t = threadIdx.x, lane = t & 63, qd = lane >> 4,      \
            l16 = lane & 15, wave = t >> 6;                      \
  const int wm = (wave >> 1) * 64, wn = (wave & 1) * 64;         \
  (void)t;

// C/D layout (verified m89/m91, dtype-independent): col = lane&15, row = quad*4 + reg

// qkv GEMM (bf16, natural block mapping): permuted-B staging; epilogue applies
// ternary rope via shfl_xor(1), writes q,k as fp8 and v as bf16.
__global__ __launch_bounds__(256) void k_gemm_qkv(const u16* __restrict__ A, const u16* __restrict__ Bt,
                                                  const float* __restrict__ bias,
                                                  const short* __restrict__ cst,
                                                  u8* __restrict__ q, u8* __restrict__ k,
                                                  u16* __restrict__ v) {
  __shared__ alignas(16) u16 As[4096], Bs[4096];
  ACC_INIT();
  const int m0 = blockIdx.y * 128, n0 = blockIdx.x * 128;
  gemm_tile<1>(A, 1024, Bt, 1024, 1024, m0, n0, As, Bs, acc);
  GEMM_EPI_IDX();
  const int sec = n0 >> 10;          // 0=q 1=k 2=v (uniform per block)
  if (sec == 2) {
#pragma unroll
    for (int i = 0; i < 4; i++) {
      const int mb = m0 + wm + i * 16 + qd * 4;
#pragma unroll
      for (int j = 0; j < 4; j++) {
        const int col = n0 + wn + j * 16 + l16;
        const float bv = bias[col];
#pragma unroll
        for (int r = 0; r < 4; r++)
          v[(size_t)(mb + r) * 1024 + (col - 2048)] = f2b(acc[i][j][r] + bv);
      }
    }
  } else {
    u8* dst = (sec == 0) ? q : k;
#pragma unroll
    for (int i = 0; i < 4; i++) {
      const int mb = m0 + wm + i * 16 + qd * 4;
#pragma unroll
      for (int j = 0; j < 4; j++) {
        const int n = n0 + wn + j * 16 + l16;           // permuted col
        const int w = n & 1023;
        const int odd = w & 1;
        const int p = w >> 1;                           // rope pair index 0..511
        const int physw = odd ? p + 512 : p;
        const float bv = bias[(n & ~1023) | physw];
        const ushort4 cs4 = *(const ushort4*)(cst + (p << 12) + (mb & 4095));
#pragma unroll
        for (int r = 0; r < 4; r++) {
          const unsigned short cspack = (r == 0) ? cs4.x : (r == 1) ? cs4.y : (r == 2) ? cs4.z : cs4.w;
          const float c = (float)(signed char)(cspack & 0xff);
          const float s = (float)(signed char)(cspack >> 8);
          const float val = acc[i][j][r] + bv;
          const float partner = __shfl_xor(val, 1);
          const float outv = odd ? (val * c + partner * s) : (val * c - partner * s);
          dst[(size_t)(mb + r) * 1024 + physw] = f2f8(outv);
        }
      }
    }
  }
}

// P = 3^(q k^T / 32) fp8, row sums ls (of the quantized values). XCD 16m x 8n.
__global__ __launch_bounds__(256) void k_gemm_scores(const u8* __restrict__ q, const u8* __restrict__ kk,
                                                     u8* __restrict__ P, float* __restrict__ ls, int b0) {
  __shared__ alignas(16) u8 As[8192], Bs[8192];
  ACC_INIT();
  const int zz = blockIdx.z, b = b0 + zz;
  const u8* A = q + (size_t)b * 4096 * 1024;
  const u8* Bt = kk + (size_t)b * 4096 * 1024;
  const int bid = blockIdx.y * 32 + blockIdx.x;
  const int xcd = bid & 7, idx = bid >> 3;
  const int m0 = ((xcd >> 2) * 16 + (idx & 15)) * 128;
  const int n0 = ((xcd & 3) * 8 + (idx >> 4)) * 128;
  gemm_tile_f8(A, 1024, Bt, 1024, 1024, m0, n0, As, Bs, acc);
  GEMM_EPI_IDX();
  const float C3 = 0.04953007814753613f;  // log2(3) / 32
  const size_t Pb = (size_t)zz * 4096 * 4096;
  f32x4 rowp[4];
#pragma unroll
  for (int i = 0; i < 4; i++) rowp[i] = f32x4{0.f, 0.f, 0.f, 0.f};
#pragma unroll
  for (int i = 0; i < 4; i++) {
    const int mb = m0 + wm + i * 16 + qd * 4;
#pragma unroll
    for (int j = 0; j < 4; j++) {
      const int col = n0 + wn + j * 16 + l16;
#pragma unroll
      for (int r = 0; r < 4; r++) {
        const float pv = exp2f(acc[i][j][r] * C3);
        const u8 pq = f2f8(pv);
        P[Pb + (size_t)(mb + r) * 4096 + col] = pq;
        rowp[i][r] += f82f(pq);   // numerator/denominator consistent
      }
    }
  }
#pragma unroll
  for (int m = 1; m < 16; m <<= 1)
#pragma unroll
    for (int i = 0; i < 4; i++) {
      rowp[i].x += __shfl_xor(rowp[i].x, m);
      rowp[i].y += __shfl_xor(rowp[i].y, m);
      rowp[i].z += __shfl_xor(rowp[i].z, m);
      rowp[i].w += __shfl_xor(rowp[i].w, m);
    }
  if (l16 == 0) {
#pragma unroll
    for (int i = 0; i < 4; i++) {
      const int mb = m0 + wm + i * 16 + qd * 4;
#pragma unroll
      for (int r = 0; r < 4; r++)
        atomicAdd(ls + (size_t)b * 4096 + mb + r, rowp[i][r]);
    }
  }
}

// o = (P @ V) / ls  (fp8 x fp8 -> bf16). XCD 8m x 4n.
__global__ __launch_bounds__(256) void k_gemm_pv(const u8* __restrict__ P, const u8* __restrict__ vt,
                                                 const float* __restrict__ ls, u16* __restrict__ o, int b0) {
  __shared__ alignas(16) u8 As[8192], Bs[8192];
  ACC_INIT();
  const int zz = blockIdx.z, b = b0 + zz;
  const u8* A = P + (size_t)zz * 4096 * 4096;
  const u8* Bt = vt + (size_t)b * 1024 * 4096;
  const int bid = blockIdx.y * 8 + blockIdx.x;
  const int xcd = bid & 7, idx = bid >> 3;
  const int m0 = ((xcd >> 1) * 8 + (idx & 7)) * 128;
  const int n0 = ((xcd & 1) * 4 + (idx >> 3)) * 128;
  gemm_tile_f8(A, 4096, Bt, 4096, 4096, m0, n0, As, Bs, acc);
  GEMM_EPI_IDX();
#pragma unroll
  for (int i = 0; i < 4; i++) {
    const int mb = m0 + wm + i * 16 + qd * 4;
    f32x4 inv;
#pragma unroll
    for (int r = 0; r < 4; r++) inv[r] = 1.0f / ls[(size_t)b * 4096 + mb + r];
#pragma unroll
    for (int j = 0; j < 4; j++) {
      const int col = n0 + wn + j * 16 + l16;
#pragma unroll
      for (int r = 0; r < 4; r++)
        o[(size_t)(b * 4096 + mb + r) * 1024 + col] = f2b(acc[i][j][r] * inv[r]);
    }
  }
}

// out = o @ WprojT^T + bias + x  (bf16 GEMM, natural mapping, fp32 out)
__global__ __launch_bounds__(256) void k_gemm_proj(const u16* __restrict__ A, const u16* __restrict__ Bt,
                                                   const float* __restrict__ bias, const float* __restrict__ x,
                                                   float* __restrict__ out) {
  __shared__ alignas(16) u16 As[4096], Bs[4096];
  ACC_INIT();
  const int m0 = blockIdx.y * 128, n0 = blockIdx.x * 128;
  gemm_tile<0>(A, 1024, Bt, 1024, 1024, m0, n0, As, Bs, acc);
  GEMM_EPI_IDX();
#pragma unroll
  for (int i = 0; i < 4; i++) {
    const int mb = m0 + wm + i * 16 + qd * 4;
#pragma unroll
    for (int j = 0; j < 4; j++) {
      const int col = n0 + wn + j * 16 + l16;
      const float bv = bias[col];
#pragma unroll
      for (int r = 0; r < 4; r++) {
        const size_t idxo = (size_t)(mb + r) * 1024 + col;
        out[idxo] = acc[i][j][r] + bv + x[idxo];
      }
    }
  }
}

// =======================================================================
extern "C" void kernel_launch(void* const* d_in, const int* in_sizes, int n_in,
                              void* d_out, int out_size, void* d_ws, size_t ws_size,
                              hipStream_t stream) {
  const float* x     = (const float*)d_in[0];
  const float* g     = (const float*)d_in[1];
  const float* wqkv  = (const float*)d_in[2];
  const float* bqkv  = (const float*)d_in[3];
  const float* wproj = (const float*)d_in[4];
  const float* bproj = (const float*)d_in[5];
  float* out = (float*)d_out;

  char* wsp = (char*)d_ws;
  size_t off = 0;
  auto take = [&](size_t bytes) -> void* {
    off = (off + 255) & ~(size_t)255;
    void* r = wsp + off;
    off += bytes;
    return r;
  };
  u16* h    = (u16*)take(16384ull * 1024 * 2);   // rmsnorm out; reused as o (PV out)
  u16* wqT  = (u16*)take(3072ull * 1024 * 2);
  u16* wpT  = (u16*)take(1024ull * 1024 * 2);
  u8*  q    = (u8*)take(16384ull * 1024);
  u8*  k    = (u8*)take(16384ull * 1024);
  u16* v    = (u16*)take(16384ull * 1024 * 2);
  u8*  vt   = (u8*)take(4ull * 1024 * 4096);
  short* cst = (short*)take(512ull * 4096 * 2);
  float* ls = (float*)take(16384ull * 4);
  off = (off + 255) & ~(size_t)255;
  int nb = 4;
  while (nb > 1 && off + (size_t)nb * 4096 * 4096 > ws_size) nb >>= 1;
  u8* P = (u8*)(wsp + off);

  k_cs_table<<<8192, 256, 0, stream>>>(cst);
  k_transpose_cast<<<dim3(3072 / 32, 1024 / 32), dim3(32, 8), 0, stream>>>(wqkv, 1024, 3072, wqT);
  k_transpose_cast<<<dim3(1024 / 32, 1024 / 32), dim3(32, 8), 0, stream>>>(wproj, 1024, 1024, wpT);
  k_rmsnorm<<<16384, 256, 0, stream>>>(x, g, h);
  k_gemm_qkv<<<dim3(24, 128), 256, 0, stream>>>(h, wqT, bqkv, cst, q, k, v);
  k_vt<<<dim3(128, 32, 4), dim3(32, 8), 0, stream>>>(v, vt);
  hipMemsetAsync(ls, 0, 16384 * 4, stream);
  for (int b0 = 0; b0 < 4; b0 += nb) {
    k_gemm_scores<<<dim3(32, 32, nb), 256, 0, stream>>>(q, k, P, ls, b0);
    k_gemm_pv<<<dim3(8, 32, nb), 256, 0, stream>>>(P, vt, ls, h /*=o*/, b0);
  }
  k_gemm_proj<<<dim3(8, 128), 256, 0, stream>>>(h /*=o*/, wpT, bproj, x, out);
}

// Round 5
// 627.944 us; speedup vs baseline: 1.5310x; 1.0482x over previous
//
#include <hip/hip_runtime.h>
#include <hip/hip_fp8.h>
#include <stdint.h>

#define DEVI __device__ __forceinline__

typedef unsigned short u16;
typedef uint8_t u8;
typedef __attribute__((ext_vector_type(8))) __bf16 bf16x8;   // MFMA bf16 A/B frag
typedef __attribute__((ext_vector_type(4))) float f32x4;     // MFMA C/D frag

DEVI float b2f(u16 u) { union { unsigned int i; float f; } v; v.i = ((unsigned int)u) << 16; return v.f; }
DEVI u16 f2b(float f) {
  union { float f; unsigned int i; } v; v.f = f;
  unsigned int r = v.i + 0x7fffu + ((v.i >> 16) & 1u);
  return (u16)(r >> 16);
}
DEVI u8 f2f8(float f) { __hip_fp8_e4m3 t(f); return t.__x; }
DEVI float f82f(u8 u) { __hip_fp8_e4m3 t; t.__x = u; return (float)t; }

DEVI void gld_lds16(const void* g, void* l) {
  __builtin_amdgcn_global_load_lds((const __attribute__((address_space(1))) unsigned int*)g,
                                   (__attribute__((address_space(3))) unsigned int*)l, 16, 0, 0);
}

// =======================================================================
// Prep / elementwise kernels
// =======================================================================

__global__ __launch_bounds__(256) void k_rmsnorm(const float* __restrict__ x,
                                                 const float* __restrict__ g,
                                                 u16* __restrict__ h) {
  const int row = blockIdx.x;
  const int t = threadIdx.x;
  const float4 v = ((const float4*)(x + (size_t)row * 1024))[t];
  float ss = v.x * v.x + v.y * v.y + v.z * v.z + v.w * v.w;
  for (int off = 32; off > 0; off >>= 1) ss += __shfl_down(ss, off);
  __shared__ float red[4];
  if ((t & 63) == 0) red[t >> 6] = ss;
  __syncthreads();
  const float tot = red[0] + red[1] + red[2] + red[3];
  const float sc = rsqrtf(tot * (1.0f / 1024.0f) + 1e-6f);
  const float4 gv = ((const float4*)g)[t];
  ushort4 o;
  o.x = f2b(v.x * sc * gv.x); o.y = f2b(v.y * sc * gv.y);
  o.z = f2b(v.z * sc * gv.z); o.w = f2b(v.w * sc * gv.w);
  *(ushort4*)(h + (size_t)row * 1024 + t * 4) = o;
}

// dst[c][r] = (bf16) src[r][c]
__global__ __launch_bounds__(256) void k_transpose_cast(const float* __restrict__ src,
                                                        int rows, int cols,
                                                        u16* __restrict__ dst) {
  __shared__ float tile[32][33];
  const int c0 = blockIdx.x * 32, r0 = blockIdx.y * 32;
  const int tx = threadIdx.x, ty = threadIdx.y;
  for (int i = 0; i < 32; i += 8)
    tile[ty + i][tx] = src[(size_t)(r0 + ty + i) * cols + c0 + tx];
  __syncthreads();
  for (int i = 0; i < 32; i += 8)
    dst[(size_t)(c0 + ty + i) * rows + r0 + tx] = f2b(tile[tx][ty + i]);
}

// ternary rope on q and k (one row each per block; shared c/s computation),
// bf16 in -> fp8 e4m3 out.
__global__ __launch_bounds__(256) void k_rope_cast(const u16* __restrict__ q16, const u16* __restrict__ k16,
                                                   u8* __restrict__ q8, u8* __restrict__ k8) {
  const int row = blockIdx.x;
  const int pos = row & 4095;
  const int t = threadIdx.x;
  const int j0 = t * 2;                       // pair indices j0, j0+1 in [0,512)
  float c[2], s[2];
#pragma unroll
  for (int u = 0; u < 2; u++) {
    const float e = (float)(j0 + u) * (1.0f / 512.0f);
    const float invf = exp2f(-13.287712379549449f * e);   // 10000^(-e)
    const float ang = (float)pos * invf;
    c[u] = rintf(cosf(ang));
    s[u] = rintf(sinf(ang));
  }
  const u16* qr = q16 + (size_t)row * 1024;
  const u16* kr = k16 + (size_t)row * 1024;
  u8* qo = q8 + (size_t)row * 1024;
  u8* ko = k8 + (size_t)row * 1024;
  const ushort2 qa = *(const ushort2*)(qr + j0), qb = *(const ushort2*)(qr + j0 + 512);
  const ushort2 ka = *(const ushort2*)(kr + j0), kb = *(const ushort2*)(kr + j0 + 512);
  uchar2 o;
  o.x = f2f8(b2f(qa.x) * c[0] - b2f(qb.x) * s[0]);
  o.y = f2f8(b2f(qa.y) * c[1] - b2f(qb.y) * s[1]);
  *(uchar2*)(qo + j0) = o;
  o.x = f2f8(b2f(qb.x) * c[0] + b2f(qa.x) * s[0]);
  o.y = f2f8(b2f(qb.y) * c[1] + b2f(qa.y) * s[1]);
  *(uchar2*)(qo + j0 + 512) = o;
  o.x = f2f8(b2f(ka.x) * c[0] - b2f(kb.x) * s[0]);
  o.y = f2f8(b2f(ka.y) * c[1] - b2f(kb.y) * s[1]);
  *(uchar2*)(ko + j0) = o;
  o.x = f2f8(b2f(kb.x) * c[0] + b2f(ka.x) * s[0]);
  o.y = f2f8(b2f(kb.y) * c[1] + b2f(ka.y) * s[1]);
  *(uchar2*)(ko + j0 + 512) = o;
}

// vt[b][d][s] = fp8( v16[(b*4096+s)*1024 + d] )
__global__ __launch_bounds__(256) void k_vt(const u16* __restrict__ v, u8* __restrict__ vt) {
  __shared__ u16 tile[32][33];
  const int b = blockIdx.z;
  const int s0 = blockIdx.x * 32, d0 = blockIdx.y * 32;
  const int tx = threadIdx.x, ty = threadIdx.y;
  for (int i = 0; i < 32; i += 8)
    tile[ty + i][tx] = v[(size_t)(b * 4096 + s0 + ty + i) * 1024 + d0 + tx];
  __syncthreads();
  for (int i = 0; i < 32; i += 8)
    vt[(size_t)(b * 1024 + d0 + ty + i) * 4096 + s0 + tx] = f2f8(b2f(tile[tx][ty + i]));
}

// =======================================================================
// bf16 MFMA GEMM core (m97 structure, BK=32)
// =======================================================================
DEVI void gemm_tile(const u16* __restrict__ A, int lda,
                    const u16* __restrict__ B, int ldb,
                    int K, int m0, int n0,
                    u16* As, u16* Bs, f32x4 acc[4][4]) {
  const int t = threadIdx.x;
  const int sr = t >> 2;
  const int sc = (t & 3) * 8;
  const u16* Ag0 = A + (size_t)(m0 + sr) * lda + sc;
  const u16* Ag1 = A + (size_t)(m0 + 64 + sr) * lda + sc;
  const u16* Bg0 = B + (size_t)(n0 + sr) * ldb + sc;
  const u16* Bg1 = B + (size_t)(n0 + 64 + sr) * ldb + sc;
  u16* Asw0 = As + t * 8;
  u16* Asw1 = As + 2048 + t * 8;
  u16* Bsw0 = Bs + t * 8;
  u16* Bsw1 = Bs + 2048 + t * 8;

  const int lane = t & 63, qd = lane >> 4, l16 = lane & 15;
  const int wave = t >> 6;
  const int wm = (wave >> 1) * 64, wn = (wave & 1) * 64;
  const u16* Ard = As + (size_t)(wm + l16) * 32 + qd * 8;
  const u16* Brd = Bs + (size_t)(wn + l16) * 32 + qd * 8;

  for (int k0 = 0; k0 < K; k0 += 32) {
    gld_lds16(Ag0 + k0, Asw0);
    gld_lds16(Ag1 + k0, Asw1);
    gld_lds16(Bg0 + k0, Bsw0);
    gld_lds16(Bg1 + k0, Bsw1);
    __builtin_amdgcn_s_waitcnt(0);
    __syncthreads();
    bf16x8 af[4], bfv[4];
#pragma unroll
    for (int i = 0; i < 4; i++) af[i] = *(const bf16x8*)(Ard + i * 16 * 32);
#pragma unroll
    for (int j = 0; j < 4; j++) bfv[j] = *(const bf16x8*)(Brd + j * 16 * 32);
#pragma unroll
    for (int i = 0; i < 4; i++)
#pragma unroll
      for (int j = 0; j < 4; j++)
        acc[i][j] = __builtin_amdgcn_mfma_f32_16x16x32_bf16(af[i], bfv[j], acc[i][j], 0, 0, 0);
    __syncthreads();
  }
}

// =======================================================================
// fp8 MFMA GEMM core (BK=64), XOR-swizzled LDS chunks (R4-verified: removes
// 10x bank conflicts; all 32 banks 4-deep = wave64 b64 minimum).
// =======================================================================
DEVI void gemm_tile_f8(const u8* __restrict__ A, int lda,
                       const u8* __restrict__ B, int ldb,
                       int K, int m0, int n0,
                       u8* As, u8* Bs, f32x4 acc[4][4]) {
  const int t = threadIdx.x;
  const int sr = t >> 2;                              // row 0..63 within half-tile
  const int sc = ((t & 3) ^ ((t >> 3) & 3)) << 4;     // swizzled global 16B chunk
  const u8* Ag0 = A + (size_t)(m0 + sr) * lda + sc;
  const u8* Ag1 = A + (size_t)(m0 + 64 + sr) * lda + sc;
  const u8* Bg0 = B + (size_t)(n0 + sr) * ldb + sc;
  const u8* Bg1 = B + (size_t)(n0 + 64 + sr) * ldb + sc;
  u8* Asw0 = As + t * 16;
  u8* Asw1 = As + 4096 + t * 16;
  u8* Bsw0 = Bs + t * 16;
  u8* Bsw1 = Bs + 4096 + t * 16;

  const int lane = t & 63, qd = lane >> 4, l16 = lane & 15;
  const int wave = t >> 6;
  const int wm = (wave >> 1) * 64, wn = (wave & 1) * 64;
  const int f = (l16 >> 1) & 3;
  const int c0 = (((qd >> 1) ^ f) << 4) + ((qd & 1) << 3);
  const u8* Ard0 = As + (size_t)(wm + l16) * 64 + c0;
  const u8* Ard1 = As + (size_t)(wm + l16) * 64 + (c0 ^ 32);
  const u8* Brd0 = Bs + (size_t)(wn + l16) * 64 + c0;
  const u8* Brd1 = Bs + (size_t)(wn + l16) * 64 + (c0 ^ 32);

  for (int k0 = 0; k0 < K; k0 += 64) {
    gld_lds16(Ag0 + k0, Asw0);
    gld_lds16(Ag1 + k0, Asw1);
    gld_lds16(Bg0 + k0, Bsw0);
    gld_lds16(Bg1 + k0, Bsw1);
    __builtin_amdgcn_s_waitcnt(0);
    __syncthreads();
    long a0[4], a1[4], b0[4], b1[4];
#pragma unroll
    for (int i = 0; i < 4; i++) {
      a0[i] = *(const long*)(Ard0 + i * 1024);
      a1[i] = *(const long*)(Ard1 + i * 1024);
    }
#pragma unroll
    for (int j = 0; j < 4; j++) {
      b0[j] = *(const long*)(Brd0 + j * 1024);
      b1[j] = *(const long*)(Brd1 + j * 1024);
    }
#pragma unroll
    for (int i = 0; i < 4; i++)
#pragma unroll
      for (int j = 0; j < 4; j++) {
        acc[i][j] = __builtin_amdgcn_mfma_f32_16x16x32_fp8_fp8(a0[i], b0[j], acc[i][j], 0, 0, 0);
        acc[i][j] = __builtin_amdgcn_mfma_f32_16x16x32_fp8_fp8(a1[i], b1[j], acc[i][j], 0, 0, 0);
      }
    __syncthreads();
  }
}

#define ACC_INIT()                                               \
  f32x4 acc[4][4];                                               \
  _Pragma("unroll") for (int i = 0; i < 4; i++)                  \
      _Pragma("unroll") for (int j = 0; j < 4; j++)              \
          acc[i][j] = f32x4{0.f, 0.f, 0.f, 0.f};

#define GEMM_EPI_IDX()                                           \
  const int t = threadIdx.x, lane = t & 63, qd = lane >> 4,      \
            l16 = lane & 15, wave = t >> 6;                      \
  const int wm = (wave >> 1) * 64, wn = (wave & 1) * 64;         \
  (void)t;

// C/D layout (verified m89/m91, dtype-independent): col = lane&15, row = quad*4 + reg

// qkv GEMM (bf16, natural mapping, LIGHT epilogue): bias + bf16 store into the
// per-section buffer (n0 never crosses a 1024-col section boundary).
__global__ __launch_bounds__(256) void k_gemm_qkv(const u16* __restrict__ A, const u16* __restrict__ Bt,
                                                  const float* __restrict__ bias,
                                                  u16* __restrict__ q16, u16* __restrict__ k16,
                                                  u16* __restrict__ v16) {
  __shared__ alignas(16) u16 As[4096], Bs[4096];
  ACC_INIT();
  const int m0 = blockIdx.y * 128, n0 = blockIdx.x * 128;
  gemm_tile(A, 1024, Bt, 1024, 1024, m0, n0, As, Bs, acc);
  GEMM_EPI_IDX();
  const int sec = n0 >> 10;                 // 0=q 1=k 2=v (uniform per block)
  u16* dst = (sec == 0) ? q16 : (sec == 1) ? k16 : v16;
  const int nb0 = n0 & 1023;
#pragma unroll
  for (int i = 0; i < 4; i++) {
    const int mb = m0 + wm + i * 16 + qd * 4;
#pragma unroll
    for (int j = 0; j < 4; j++) {
      const int col = n0 + wn + j * 16 + l16;
      const float bv = bias[col];
      const int dcol = nb0 + wn + j * 16 + l16;
#pragma unroll
      for (int r = 0; r < 4; r++)
        dst[(size_t)(mb + r) * 1024 + dcol] = f2b(acc[i][j][r] + bv);
    }
  }
}

// P = 3^(q k^T / 32) fp8, row sums ls (of the quantized values). XCD 16m x 8n.
__global__ __launch_bounds__(256) void k_gemm_scores(const u8* __restrict__ q, const u8* __restrict__ kk,
                                                     u8* __restrict__ P, float* __restrict__ ls) {
  __shared__ alignas(16) u8 As[8192], Bs[8192];
  ACC_INIT();
  const int b = blockIdx.z;
  const u8* A = q + (size_t)b * 4096 * 1024;
  const u8* Bt = kk + (size_t)b * 4096 * 1024;
  const int bid = blockIdx.y * 32 + blockIdx.x;
  const int xcd = bid & 7, idx = bid >> 3;
  const int m0 = ((xcd >> 2) * 16 + (idx & 15)) * 128;
  const int n0 = ((xcd & 3) * 8 + (idx >> 4)) * 128;
  gemm_tile_f8(A, 1024, Bt, 1024, 1024, m0, n0, As, Bs, acc);
  GEMM_EPI_IDX();
  const float C3 = 0.04953007814753613f;  // log2(3) / 32
  const size_t Pb = (size_t)b * 4096 * 4096;
  f32x4 rowp[4];
#pragma unroll
  for (int i = 0; i < 4; i++) rowp[i] = f32x4{0.f, 0.f, 0.f, 0.f};
#pragma unroll
  for (int i = 0; i < 4; i++) {
    const int mb = m0 + wm + i * 16 + qd * 4;
#pragma unroll
    for (int j = 0; j < 4; j++) {
      const int col = n0 + wn + j * 16 + l16;
#pragma unroll
      for (int r = 0; r < 4; r++) {
        const float pv = exp2f(acc[i][j][r] * C3);
        const u8 pq = f2f8(pv);
        P[Pb + (size_t)(mb + r) * 4096 + col] = pq;
        rowp[i][r] += f82f(pq);   // numerator/denominator consistent
      }
    }
  }
#pragma unroll
  for (int m = 1; m < 16; m <<= 1)
#pragma unroll
    for (int i = 0; i < 4; i++) {
      rowp[i].x += __shfl_xor(rowp[i].x, m);
      rowp[i].y += __shfl_xor(rowp[i].y, m);
      rowp[i].z += __shfl_xor(rowp[i].z, m);
      rowp[i].w += __shfl_xor(rowp[i].w, m);
    }
  if (l16 == 0) {
#pragma unroll
    for (int i = 0; i < 4; i++) {
      const int mb = m0 + wm + i * 16 + qd * 4;
#pragma unroll
      for (int r = 0; r < 4; r++)
        atomicAdd(ls + (size_t)b * 4096 + mb + r, rowp[i][r]);
    }
  }
}

// o = (P @ V) / ls  (fp8 x fp8 -> bf16). XCD 8m x 4n.
__global__ __launch_bounds__(256) void k_gemm_pv(const u8* __restrict__ P, const u8* __restrict__ vt,
                                                 const float* __restrict__ ls, u16* __restrict__ o) {
  __shared__ alignas(16) u8 As[8192], Bs[8192];
  ACC_INIT();
  const int b = blockIdx.z;
  const u8* A = P + (size_t)b * 4096 * 4096;
  const u8* Bt = vt + (size_t)b * 1024 * 4096;
  const int bid = blockIdx.y * 8 + blockIdx.x;
  const int xcd = bid & 7, idx = bid >> 3;
  const int m0 = ((xcd >> 1) * 8 + (idx & 7)) * 128;
  const int n0 = ((xcd & 1) * 4 + (idx >> 3)) * 128;
  gemm_tile_f8(A, 4096, Bt, 4096, 4096, m0, n0, As, Bs, acc);
  GEMM_EPI_IDX();
#pragma unroll
  for (int i = 0; i < 4; i++) {
    const int mb = m0 + wm + i * 16 + qd * 4;
    f32x4 inv;
#pragma unroll
    for (int r = 0; r < 4; r++) inv[r] = 1.0f / ls[(size_t)b * 4096 + mb + r];
#pragma unroll
    for (int j = 0; j < 4; j++) {
      const int col = n0 + wn + j * 16 + l16;
#pragma unroll
      for (int r = 0; r < 4; r++)
        o[(size_t)(b * 4096 + mb + r) * 1024 + col] = f2b(acc[i][j][r] * inv[r]);
    }
  }
}

// out = o @ WprojT^T + bias + x  (bf16 GEMM, natural mapping, fp32 out)
__global__ __launch_bounds__(256) void k_gemm_proj(const u16* __restrict__ A, const u16* __restrict__ Bt,
                                                   const float* __restrict__ bias, const float* __restrict__ x,
                                                   float* __restrict__ out) {
  __shared__ alignas(16) u16 As[4096], Bs[4096];
  ACC_INIT();
  const int m0 = blockIdx.y * 128, n0 = blockIdx.x * 128;
  gemm_tile(A, 1024, Bt, 1024, 1024, m0, n0, As, Bs, acc);
  GEMM_EPI_IDX();
#pragma unroll
  for (int i = 0; i < 4; i++) {
    const int mb = m0 + wm + i * 16 + qd * 4;
#pragma unroll
    for (int j = 0; j < 4; j++) {
      const int col = n0 + wn + j * 16 + l16;
      const float bv = bias[col];
#pragma unroll
      for (int r = 0; r < 4; r++) {
        const size_t idxo = (size_t)(mb + r) * 1024 + col;
        out[idxo] = acc[i][j][r] + bv + x[idxo];
      }
    }
  }
}

// =======================================================================
extern "C" void kernel_launch(void* const* d_in, const int* in_sizes, int n_in,
                              void* d_out, int out_size, void* d_ws, size_t ws_size,
                              hipStream_t stream) {
  const float* x     = (const float*)d_in[0];
  const float* g     = (const float*)d_in[1];
  const float* wqkv  = (const float*)d_in[2];
  const float* bqkv  = (const float*)d_in[3];
  const float* wproj = (const float*)d_in[4];
  const float* bproj = (const float*)d_in[5];
  float* out = (float*)d_out;

  char* wsp = (char*)d_ws;
  size_t off = 0;
  auto take = [&](size_t bytes) -> void* {
    off = (off + 255) & ~(size_t)255;
    void* r = wsp + off;
    off += bytes;
    return r;
  };
  u16* h    = (u16*)take(16384ull * 1024 * 2);   // rmsnorm out; reused as o (PV out)
  u16* wqT  = (u16*)take(3072ull * 1024 * 2);
  u16* wpT  = (u16*)take(1024ull * 1024 * 2);
  u8*  q8   = (u8*)take(16384ull * 1024);
  u8*  k8   = (u8*)take(16384ull * 1024);
  u8*  vt   = (u8*)take(4ull * 1024 * 4096);
  float* ls = (float*)take(16384ull * 4);
  // scratch region: q16/k16/v16 (bf16, 96 MB) live only until rope/vt; P
  // (fp8, 67 MB for all 4 batches) aliases the same region afterwards.
  char* scratch = (char*)take(3ull * 16384 * 1024 * 2);
  u16* q16 = (u16*)scratch;
  u16* k16 = (u16*)(scratch + 16384ull * 1024 * 2);
  u16* v16 = (u16*)(scratch + 2ull * 16384 * 1024 * 2);
  u8*  P   = (u8*)scratch;

  k_transpose_cast<<<dim3(3072 / 32, 1024 / 32), dim3(32, 8), 0, stream>>>(wqkv, 1024, 3072, wqT);
  k_transpose_cast<<<dim3(1024 / 32, 1024 / 32), dim3(32, 8), 0, stream>>>(wproj, 1024, 1024, wpT);
  k_rmsnorm<<<16384, 256, 0, stream>>>(x, g, h);
  k_gemm_qkv<<<dim3(24, 128), 256, 0, stream>>>(h, wqT, bqkv, q16, k16, v16);
  k_rope_cast<<<16384, 256, 0, stream>>>(q16, k16, q8, k8);
  k_vt<<<dim3(128, 32, 4), dim3(32, 8), 0, stream>>>(v16, vt);
  hipMemsetAsync(ls, 0, 16384 * 4, stream);
  k_gemm_scores<<<dim3(32, 32, 4), 256, 0, stream>>>(q8, k8, P, ls);
  k_gemm_pv<<<dim3(8, 32, 4), 256, 0, stream>>>(P, vt, ls, h /*=o*/);
  k_gemm_proj<<<dim3(8, 128), 256, 0, stream>>>(h /*=o*/, wpT, bproj, x, out);
}

// Round 6
// 601.279 us; speedup vs baseline: 1.5989x; 1.0443x over previous
//
#include <hip/hip_runtime.h>
#include <hip/hip_fp8.h>
#include <stdint.h>

#define DEVI __device__ __forceinline__

typedef unsigned short u16;
typedef uint8_t u8;
typedef __attribute__((ext_vector_type(8))) __bf16 bf16x8;   // MFMA bf16 A/B frag
typedef __attribute__((ext_vector_type(4))) float f32x4;     // MFMA C/D frag

DEVI float b2f(u16 u) { union { unsigned int i; float f; } v; v.i = ((unsigned int)u) << 16; return v.f; }
DEVI u16 f2b(float f) {
  union { float f; unsigned int i; } v; v.f = f;
  unsigned int r = v.i + 0x7fffu + ((v.i >> 16) & 1u);
  return (u16)(r >> 16);
}
DEVI u8 f2f8(float f) { __hip_fp8_e4m3 t(f); return t.__x; }

DEVI void gld_lds16(const void* g, void* l) {
  __builtin_amdgcn_global_load_lds((const __attribute__((address_space(1))) unsigned int*)g,
                                   (__attribute__((address_space(3))) unsigned int*)l, 16, 0, 0);
}

// =======================================================================
// Prep / elementwise kernels
// =======================================================================

__global__ __launch_bounds__(256) void k_rmsnorm(const float* __restrict__ x,
                                                 const float* __restrict__ g,
                                                 u16* __restrict__ h) {
  const int row = blockIdx.x;
  const int t = threadIdx.x;
  const float4 v = ((const float4*)(x + (size_t)row * 1024))[t];
  float ss = v.x * v.x + v.y * v.y + v.z * v.z + v.w * v.w;
  for (int off = 32; off > 0; off >>= 1) ss += __shfl_down(ss, off);
  __shared__ float red[4];
  if ((t & 63) == 0) red[t >> 6] = ss;
  __syncthreads();
  const float tot = red[0] + red[1] + red[2] + red[3];
  const float sc = rsqrtf(tot * (1.0f / 1024.0f) + 1e-6f);
  const float4 gv = ((const float4*)g)[t];
  ushort4 o;
  o.x = f2b(v.x * sc * gv.x); o.y = f2b(v.y * sc * gv.y);
  o.z = f2b(v.z * sc * gv.z); o.w = f2b(v.w * sc * gv.w);
  *(ushort4*)(h + (size_t)row * 1024 + t * 4) = o;
}

// dst[c][r] = (bf16) src[r][c]
__global__ __launch_bounds__(256) void k_transpose_cast(const float* __restrict__ src,
                                                        int rows, int cols,
                                                        u16* __restrict__ dst) {
  __shared__ float tile[32][33];
  const int c0 = blockIdx.x * 32, r0 = blockIdx.y * 32;
  const int tx = threadIdx.x, ty = threadIdx.y;
  for (int i = 0; i < 32; i += 8)
    tile[ty + i][tx] = src[(size_t)(r0 + ty + i) * cols + c0 + tx];
  __syncthreads();
  for (int i = 0; i < 32; i += 8)
    dst[(size_t)(c0 + ty + i) * rows + r0 + tx] = f2b(tile[tx][ty + i]);
}

// ternary rope on q and k (one row each per block; shared c/s computation),
// bf16 in -> fp8 e4m3 out.
__global__ __launch_bounds__(256) void k_rope_cast(const u16* __restrict__ q16, const u16* __restrict__ k16,
                                                   u8* __restrict__ q8, u8* __restrict__ k8) {
  const int row = blockIdx.x;
  const int pos = row & 4095;
  const int t = threadIdx.x;
  const int j0 = t * 2;                       // pair indices j0, j0+1 in [0,512)
  float c[2], s[2];
#pragma unroll
  for (int u = 0; u < 2; u++) {
    const float e = (float)(j0 + u) * (1.0f / 512.0f);
    const float invf = exp2f(-13.287712379549449f * e);   // 10000^(-e)
    const float ang = (float)pos * invf;
    c[u] = rintf(cosf(ang));
    s[u] = rintf(sinf(ang));
  }
  const u16* qr = q16 + (size_t)row * 1024;
  const u16* kr = k16 + (size_t)row * 1024;
  u8* qo = q8 + (size_t)row * 1024;
  u8* ko = k8 + (size_t)row * 1024;
  const ushort2 qa = *(const ushort2*)(qr + j0), qb = *(const ushort2*)(qr + j0 + 512);
  const ushort2 ka = *(const ushort2*)(kr + j0), kb = *(const ushort2*)(kr + j0 + 512);
  uchar2 o;
  o.x = f2f8(b2f(qa.x) * c[0] - b2f(qb.x) * s[0]);
  o.y = f2f8(b2f(qa.y) * c[1] - b2f(qb.y) * s[1]);
  *(uchar2*)(qo + j0) = o;
  o.x = f2f8(b2f(qb.x) * c[0] + b2f(qa.x) * s[0]);
  o.y = f2f8(b2f(qb.y) * c[1] + b2f(qa.y) * s[1]);
  *(uchar2*)(qo + j0 + 512) = o;
  o.x = f2f8(b2f(ka.x) * c[0] - b2f(kb.x) * s[0]);
  o.y = f2f8(b2f(ka.y) * c[1] - b2f(kb.y) * s[1]);
  *(uchar2*)(ko + j0) = o;
  o.x = f2f8(b2f(kb.x) * c[0] + b2f(ka.x) * s[0]);
  o.y = f2f8(b2f(kb.y) * c[1] + b2f(ka.y) * s[1]);
  *(uchar2*)(ko + j0 + 512) = o;
}

// vt[b][d][s] = fp8( v16[(b*4096+s)*1024 + d] )
__global__ __launch_bounds__(256) void k_vt(const u16* __restrict__ v, u8* __restrict__ vt) {
  __shared__ u16 tile[32][33];
  const int b = blockIdx.z;
  const int s0 = blockIdx.x * 32, d0 = blockIdx.y * 32;
  const int tx = threadIdx.x, ty = threadIdx.y;
  for (int i = 0; i < 32; i += 8)
    tile[ty + i][tx] = v[(size_t)(b * 4096 + s0 + ty + i) * 1024 + d0 + tx];
  __syncthreads();
  for (int i = 0; i < 32; i += 8)
    vt[(size_t)(b * 1024 + d0 + ty + i) * 4096 + s0 + tx] = f2f8(b2f(tile[tx][ty + i]));
}

// =======================================================================
// bf16 MFMA GEMM core (m97 structure, BK=32) — for qkv / proj (K=1024 bf16)
// =======================================================================
DEVI void gemm_tile(const u16* __restrict__ A, int lda,
                    const u16* __restrict__ B, int ldb,
                    int K, int m0, int n0,
                    u16* As, u16* Bs, f32x4 acc[4][4]) {
  const int t = threadIdx.x;
  const int sr = t >> 2;
  const int sc = (t & 3) * 8;
  const u16* Ag0 = A + (size_t)(m0 + sr) * lda + sc;
  const u16* Ag1 = A + (size_t)(m0 + 64 + sr) * lda + sc;
  const u16* Bg0 = B + (size_t)(n0 + sr) * ldb + sc;
  const u16* Bg1 = B + (size_t)(n0 + 64 + sr) * ldb + sc;
  u16* Asw0 = As + t * 8;
  u16* Asw1 = As + 2048 + t * 8;
  u16* Bsw0 = Bs + t * 8;
  u16* Bsw1 = Bs + 2048 + t * 8;

  const int lane = t & 63, qd = lane >> 4, l16 = lane & 15;
  const int wave = t >> 6;
  const int wm = (wave >> 1) * 64, wn = (wave & 1) * 64;
  const u16* Ard = As + (size_t)(wm + l16) * 32 + qd * 8;
  const u16* Brd = Bs + (size_t)(wn + l16) * 32 + qd * 8;

  for (int k0 = 0; k0 < K; k0 += 32) {
    gld_lds16(Ag0 + k0, Asw0);
    gld_lds16(Ag1 + k0, Asw1);
    gld_lds16(Bg0 + k0, Bsw0);
    gld_lds16(Bg1 + k0, Bsw1);
    __builtin_amdgcn_s_waitcnt(0);
    __syncthreads();
    bf16x8 af[4], bfv[4];
#pragma unroll
    for (int i = 0; i < 4; i++) af[i] = *(const bf16x8*)(Ard + i * 16 * 32);
#pragma unroll
    for (int j = 0; j < 4; j++) bfv[j] = *(const bf16x8*)(Brd + j * 16 * 32);
#pragma unroll
    for (int i = 0; i < 4; i++)
#pragma unroll
      for (int j = 0; j < 4; j++)
        acc[i][j] = __builtin_amdgcn_mfma_f32_16x16x32_bf16(af[i], bfv[j], acc[i][j], 0, 0, 0);
    __syncthreads();
  }
}

// =======================================================================
// fp8 MFMA GEMM core, BK=128 (8 K-iters at K=1024): 16 KB LDS per operand,
// 8 gld_lds16/thread in flight per barrier drain, 64 MFMA/wave per barrier.
// XOR swizzle widened to 8 chunks with key = row&7.
// Bank check (b64 reads): per wave-read, 4 accesses per touched bank-quad =
// 4 clk = wave64 b64 minimum (64 lanes x 8 B / 128 B-per-clk LDS peak).
// =======================================================================
DEVI void gemm_tile_f8(const u8* __restrict__ A, int lda,
                       const u8* __restrict__ B, int ldb,
                       int K, int m0, int n0,
                       u8* As, u8* Bs, f32x4 acc[4][4]) {
  const int t = threadIdx.x;
  const int sr = t >> 3;                              // row 0..31 within 32-row group
  const int sc = ((t & 7) ^ (sr & 7)) << 4;           // swizzled global 16B chunk
  const u8* Agb = A + (size_t)(m0 + sr) * lda + sc;   // + l*32*lda + k0
  const u8* Bgb = B + (size_t)(n0 + sr) * ldb + sc;
  u8* Asw = As + t * 16;                              // + l*4096
  u8* Bsw = Bs + t * 16;

  const int lane = t & 63, qd = lane >> 4, l16 = lane & 15;
  const int wave = t >> 6;
  const int wm = (wave >> 1) * 64, wn = (wave & 1) * 64;
  const int key = l16 & 7;                            // == frag row & 7
  const int sub = (qd & 1) << 3;                      // byte within chunk
  // chunk for k-group g: c = g*2 + (qd>>1); addr = row*128 + ((c^key)<<4) + sub
  const u8* Arow = As + (size_t)(wm + l16) * 128;
  const u8* Brow = Bs + (size_t)(wn + l16) * 128;
  const int qh = qd >> 1;

  for (int k0 = 0; k0 < K; k0 += 128) {
#pragma unroll
    for (int l = 0; l < 4; l++) {
      gld_lds16(Agb + k0 + (size_t)l * 32 * lda, Asw + l * 4096);
      gld_lds16(Bgb + k0 + (size_t)l * 32 * ldb, Bsw + l * 4096);
    }
    __builtin_amdgcn_s_waitcnt(0);
    __syncthreads();
#pragma unroll
    for (int g = 0; g < 4; g++) {
      const int coff = (((g * 2 + qh) ^ key) << 4) + sub;
      long a[4], b[4];
#pragma unroll
      for (int i = 0; i < 4; i++) a[i] = *(const long*)(Arow + i * 16 * 128 + coff);
#pragma unroll
      for (int j = 0; j < 4; j++) b[j] = *(const long*)(Brow + j * 16 * 128 + coff);
#pragma unroll
      for (int i = 0; i < 4; i++)
#pragma unroll
        for (int j = 0; j < 4; j++)
          acc[i][j] = __builtin_amdgcn_mfma_f32_16x16x32_fp8_fp8(a[i], b[j], acc[i][j], 0, 0, 0);
    }
    __syncthreads();
  }
}

#define ACC_INIT()                                               \
  f32x4 acc[4][4];                                               \
  _Pragma("unroll") for (int i = 0; i < 4; i++)                  \
      _Pragma("unroll") for (int j = 0; j < 4; j++)              \
          acc[i][j] = f32x4{0.f, 0.f, 0.f, 0.f};

#define GEMM_EPI_IDX()                                           \
  const int t = threadIdx.x, lane = t & 63, qd = lane >> 4,      \
            l16 = lane & 15, wave = t >> 6;                      \
  const int wm = (wave >> 1) * 64, wn = (wave & 1) * 64;         \
  (void)t;

// C/D layout (verified m89/m91, dtype-independent): col = lane&15, row = quad*4 + reg

// qkv GEMM (bf16, natural mapping, light epilogue)
__global__ __launch_bounds__(256) void k_gemm_qkv(const u16* __restrict__ A, const u16* __restrict__ Bt,
                                                  const float* __restrict__ bias,
                                                  u16* __restrict__ q16, u16* __restrict__ k16,
                                                  u16* __restrict__ v16) {
  __shared__ alignas(16) u16 As[4096], Bs[4096];
  ACC_INIT();
  const int m0 = blockIdx.y * 128, n0 = blockIdx.x * 128;
  gemm_tile(A, 1024, Bt, 1024, 1024, m0, n0, As, Bs, acc);
  GEMM_EPI_IDX();
  const int sec = n0 >> 10;                 // 0=q 1=k 2=v (uniform per block)
  u16* dst = (sec == 0) ? q16 : (sec == 1) ? k16 : v16;
  const int nb0 = n0 & 1023;
#pragma unroll
  for (int i = 0; i < 4; i++) {
    const int mb = m0 + wm + i * 16 + qd * 4;
#pragma unroll
    for (int j = 0; j < 4; j++) {
      const int col = n0 + wn + j * 16 + l16;
      const float bv = bias[col];
      const int dcol = nb0 + wn + j * 16 + l16;
#pragma unroll
      for (int r = 0; r < 4; r++)
        dst[(size_t)(mb + r) * 1024 + dcol] = f2b(acc[i][j][r] + bv);
    }
  }
}

// P = 3^(q k^T / 32) fp8, row sums ls (float, pre-quantization). XCD 16m x 8n.
__global__ __launch_bounds__(256) void k_gemm_scores(const u8* __restrict__ q, const u8* __restrict__ kk,
                                                     u8* __restrict__ P, float* __restrict__ ls) {
  __shared__ alignas(16) u8 As[16384], Bs[16384];
  ACC_INIT();
  const int b = blockIdx.z;
  const u8* A = q + (size_t)b * 4096 * 1024;
  const u8* Bt = kk + (size_t)b * 4096 * 1024;
  const int bid = blockIdx.y * 32 + blockIdx.x;
  const int xcd = bid & 7, idx = bid >> 3;
  const int m0 = ((xcd >> 2) * 16 + (idx & 15)) * 128;
  const int n0 = ((xcd & 3) * 8 + (idx >> 4)) * 128;
  gemm_tile_f8(A, 1024, Bt, 1024, 1024, m0, n0, As, Bs, acc);
  GEMM_EPI_IDX();
  const float C3 = 0.04953007814753613f;  // log2(3) / 32
  const size_t Pb = (size_t)b * 4096 * 4096;
  f32x4 rowp[4];
#pragma unroll
  for (int i = 0; i < 4; i++) rowp[i] = f32x4{0.f, 0.f, 0.f, 0.f};
#pragma unroll
  for (int i = 0; i < 4; i++) {
    const int mb = m0 + wm + i * 16 + qd * 4;
#pragma unroll
    for (int j = 0; j < 4; j++) {
      const int col = n0 + wn + j * 16 + l16;
#pragma unroll
      for (int r = 0; r < 4; r++) {
        const float pv = exp2f(acc[i][j][r] * C3);
        P[Pb + (size_t)(mb + r) * 4096 + col] = f2f8(pv);
        rowp[i][r] += pv;
      }
    }
  }
#pragma unroll
  for (int m = 1; m < 16; m <<= 1)
#pragma unroll
    for (int i = 0; i < 4; i++) {
      rowp[i].x += __shfl_xor(rowp[i].x, m);
      rowp[i].y += __shfl_xor(rowp[i].y, m);
      rowp[i].z += __shfl_xor(rowp[i].z, m);
      rowp[i].w += __shfl_xor(rowp[i].w, m);
    }
  if (l16 == 0) {
#pragma unroll
    for (int i = 0; i < 4; i++) {
      const int mb = m0 + wm + i * 16 + qd * 4;
#pragma unroll
      for (int r = 0; r < 4; r++)
        atomicAdd(ls + (size_t)b * 4096 + mb + r, rowp[i][r]);
    }
  }
}

// o = (P @ V) / ls  (fp8 x fp8 -> bf16). XCD 8m x 4n.
__global__ __launch_bounds__(256) void k_gemm_pv(const u8* __restrict__ P, const u8* __restrict__ vt,
                                                 const float* __restrict__ ls, u16* __restrict__ o) {
  __shared__ alignas(16) u8 As[16384], Bs[16384];
  ACC_INIT();
  const int b = blockIdx.z;
  const u8* A = P + (size_t)b * 4096 * 4096;
  const u8* Bt = vt + (size_t)b * 1024 * 4096;
  const int bid = blockIdx.y * 8 + blockIdx.x;
  const int xcd = bid & 7, idx = bid >> 3;
  const int m0 = ((xcd >> 1) * 8 + (idx & 7)) * 128;
  const int n0 = ((xcd & 1) * 4 + (idx >> 3)) * 128;
  gemm_tile_f8(A, 4096, Bt, 4096, 4096, m0, n0, As, Bs, acc);
  GEMM_EPI_IDX();
#pragma unroll
  for (int i = 0; i < 4; i++) {
    const int mb = m0 + wm + i * 16 + qd * 4;
    f32x4 inv;
#pragma unroll
    for (int r = 0; r < 4; r++) inv[r] = 1.0f / ls[(size_t)b * 4096 + mb + r];
#pragma unroll
    for (int j = 0; j < 4; j++) {
      const int col = n0 + wn + j * 16 + l16;
#pragma unroll
      for (int r = 0; r < 4; r++)
        o[(size_t)(b * 4096 + mb + r) * 1024 + col] = f2b(acc[i][j][r] * inv[r]);
    }
  }
}

// out = o @ WprojT^T + bias + x  (bf16 GEMM, natural mapping, fp32 out)
__global__ __launch_bounds__(256) void k_gemm_proj(const u16* __restrict__ A, const u16* __restrict__ Bt,
                                                   const float* __restrict__ bias, const float* __restrict__ x,
                                                   float* __restrict__ out) {
  __shared__ alignas(16) u16 As[4096], Bs[4096];
  ACC_INIT();
  const int m0 = blockIdx.y * 128, n0 = blockIdx.x * 128;
  gemm_tile(A, 1024, Bt, 1024, 1024, m0, n0, As, Bs, acc);
  GEMM_EPI_IDX();
#pragma unroll
  for (int i = 0; i < 4; i++) {
    const int mb = m0 + wm + i * 16 + qd * 4;
#pragma unroll
    for (int j = 0; j < 4; j++) {
      const int col = n0 + wn + j * 16 + l16;
      const float bv = bias[col];
#pragma unroll
      for (int r = 0; r < 4; r++) {
        const size_t idxo = (size_t)(mb + r) * 1024 + col;
        out[idxo] = acc[i][j][r] + bv + x[idxo];
      }
    }
  }
}

// =======================================================================
extern "C" void kernel_launch(void* const* d_in, const int* in_sizes, int n_in,
                              void* d_out, int out_size, void* d_ws, size_t ws_size,
                              hipStream_t stream) {
  const float* x     = (const float*)d_in[0];
  const float* g     = (const float*)d_in[1];
  const float* wqkv  = (const float*)d_in[2];
  const float* bqkv  = (const float*)d_in[3];
  const float* wproj = (const float*)d_in[4];
  const float* bproj = (const float*)d_in[5];
  float* out = (float*)d_out;

  char* wsp = (char*)d_ws;
  size_t off = 0;
  auto take = [&](size_t bytes) -> void* {
    off = (off + 255) & ~(size_t)255;
    void* r = wsp + off;
    off += bytes;
    return r;
  };
  u16* h    = (u16*)take(16384ull * 1024 * 2);   // rmsnorm out; reused as o (PV out)
  u16* wqT  = (u16*)take(3072ull * 1024 * 2);
  u16* wpT  = (u16*)take(1024ull * 1024 * 2);
  u8*  q8   = (u8*)take(16384ull * 1024);
  u8*  k8   = (u8*)take(16384ull * 1024);
  u8*  vt   = (u8*)take(4ull * 1024 * 4096);
  float* ls = (float*)take(16384ull * 4);
  // scratch region: q16/k16/v16 (bf16, 96 MB) live only until rope/vt; P
  // (fp8, 67 MB for all 4 batches) aliases the same region afterwards.
  char* scratch = (char*)take(3ull * 16384 * 1024 * 2);
  u16* q16 = (u16*)scratch;
  u16* k16 = (u16*)(scratch + 16384ull * 1024 * 2);
  u16* v16 = (u16*)(scratch + 2ull * 16384 * 1024 * 2);
  u8*  P   = (u8*)scratch;

  k_transpose_cast<<<dim3(3072 / 32, 1024 / 32), dim3(32, 8), 0, stream>>>(wqkv, 1024, 3072, wqT);
  k_transpose_cast<<<dim3(1024 / 32, 1024 / 32), dim3(32, 8), 0, stream>>>(wproj, 1024, 1024, wpT);
  k_rmsnorm<<<16384, 256, 0, stream>>>(x, g, h);
  k_gemm_qkv<<<dim3(24, 128), 256, 0, stream>>>(h, wqT, bqkv, q16, k16, v16);
  k_rope_cast<<<16384, 256, 0, stream>>>(q16, k16, q8, k8);
  k_vt<<<dim3(128, 32, 4), dim3(32, 8), 0, stream>>>(v16, vt);
  hipMemsetAsync(ls, 0, 16384 * 4, stream);
  k_gemm_scores<<<dim3(32, 32, 4), 256, 0, stream>>>(q8, k8, P, ls);
  k_gemm_pv<<<dim3(8, 32, 4), 256, 0, stream>>>(P, vt, ls, h /*=o*/);
  k_gemm_proj<<<dim3(8, 128), 256, 0, stream>>>(h /*=o*/, wpT, bproj, x, out);
}